// Round 2
// baseline (205.844 us; speedup 1.0000x reference)
//
#include <hip/hip_runtime.h>
#include <hip/hip_bf16.h>
#include <stdint.h>

// L=32, B=8, A=128, D=256, H=8, hd=32, BA=1024, M=32768

typedef float f32x4 __attribute__((ext_vector_type(4)));
typedef short s16x8 __attribute__((ext_vector_type(8)));
typedef unsigned short u16x8 __attribute__((ext_vector_type(8)));

__device__ __forceinline__ unsigned short f2bf(float f) {
  __hip_bfloat16 h = __float2bfloat16(f);
  return __builtin_bit_cast(unsigned short, h);
}
__device__ __forceinline__ f32x4 mfma16(s16x8 a, s16x8 b, f32x4 c) {
  return __builtin_amdgcn_mfma_f32_16x16x32_bf16(a, b, c, 0, 0, 0);
}

// K0: Wt[s][n][k] = bf16(W_s[k][n]); s: 0=Wq 1=Wk 2=Wv
__global__ void wt_kernel(const float* __restrict__ wq, const float* __restrict__ wk,
                          const float* __restrict__ wv, unsigned short* __restrict__ wt) {
  int t = blockIdx.x * 256 + threadIdx.x;           // 0..196607
  int s = t >> 16; int w = t & 65535;
  int n = w >> 8;  int k = w & 255;
  const float* W = (s == 0) ? wq : (s == 1) ? wk : wv;
  wt[t] = f2bf(W[k * 256 + n]);
}

// K1 (fused): C_s = X(32768x256) @ W_s for s in {q,k,v}; X staged once in LDS as bf16.
// 1024 blocks x 256 thr (4 waves). Block = 32 rows of X. Wave wn owns 64 cols of all 3 outputs.
__global__ __launch_bounds__(256, 3) void proj_kernel(
    const float* __restrict__ X, const unsigned short* __restrict__ wt,
    unsigned short* __restrict__ qb, unsigned short* __restrict__ kb,
    unsigned short* __restrict__ vb) {
  __shared__ unsigned short xs[32][256];   // 16 KiB, granule-XOR-swizzled
  const int tid = threadIdx.x;
  const int m0 = blockIdx.x * 32;

  // stage: 1024 granules of 8 bf16; granule gc of row stored at (gc ^ (row&7))
  #pragma unroll
  for (int kq = 0; kq < 4; ++kq) {
    int t = tid + kq * 256;
    int row = t >> 5, gc = t & 31;
    const float* src = X + (size_t)(m0 + row) * 256 + gc * 8;
    f32x4 f0 = *(const f32x4*)src;
    f32x4 f1 = *(const f32x4*)(src + 4);
    u16x8 o;
    #pragma unroll
    for (int e = 0; e < 4; ++e) { o[e] = f2bf(f0[e]); o[4 + e] = f2bf(f1[e]); }
    *(u16x8*)&xs[row][(gc ^ (row & 7)) * 8] = o;
  }
  __syncthreads();

  const int wid = tid >> 6, lane = tid & 63;
  const int row16 = lane & 15, grp = lane >> 4;
  const int wn = wid;  // 0..3

  f32x4 acc[3][2][4];
  #pragma unroll
  for (int s = 0; s < 3; ++s)
    #pragma unroll
    for (int mi = 0; mi < 2; ++mi)
      #pragma unroll
      for (int ni = 0; ni < 4; ++ni) acc[s][mi][ni] = (f32x4){0.f, 0.f, 0.f, 0.f};

  #pragma unroll
  for (int kk = 0; kk < 8; ++kk) {
    s16x8 af[2];
    #pragma unroll
    for (int mi = 0; mi < 2; ++mi)
      af[mi] = *(const s16x8*)&xs[mi * 16 + row16][((kk * 4 + grp) ^ (row16 & 7)) * 8];
    #pragma unroll
    for (int s = 0; s < 3; ++s) {
      const unsigned short* bp = wt + s * 65536 + (size_t)(wn * 64 + row16) * 256 + kk * 32 + grp * 8;
      #pragma unroll
      for (int ni = 0; ni < 4; ++ni) {
        s16x8 bf = *(const s16x8*)(bp + ni * 16 * 256);
        acc[s][0][ni] = mfma16(af[0], bf, acc[s][0][ni]);
        acc[s][1][ni] = mfma16(af[1], bf, acc[s][1][ni]);
      }
    }
  }

  // scatter to [b,h,a,l,d] bf16. Block-uniform: l = m0>>10, b = (m0>>7)&7, a0 = m0&127
  const int l = m0 >> 10, b = (m0 >> 7) & 7, a0 = m0 & 127;
  #pragma unroll
  for (int s = 0; s < 3; ++s) {
    unsigned short* dst = (s == 0) ? qb : (s == 1) ? kb : vb;
    #pragma unroll
    for (int mi = 0; mi < 2; ++mi)
      #pragma unroll
      for (int ni = 0; ni < 4; ++ni)
        #pragma unroll
        for (int r = 0; r < 4; ++r) {
          int a = a0 + mi * 16 + grp * 4 + r;
          int n = wn * 64 + ni * 16 + row16;
          int h = n >> 5, d = n & 31;
          dst[(((size_t)(b * 8 + h) * 128 + a) * 32 + l) * 32 + d] = f2bf(acc[s][mi][ni][r]);
        }
  }
}

// K1b: vw1[b,h,a,l] = sum_d v*Watt[h*32+d]; vw2 with Watt[256+...]
__global__ void vw_kernel(const unsigned short* __restrict__ vb,
                          const float* __restrict__ watt,
                          float* __restrict__ vw1, float* __restrict__ vw2) {
  int row = blockIdx.x * 256 + threadIdx.x;   // (b,h,a,l) flat, 0..262143
  int h = (row >> 12) & 7;
  const unsigned short* vp = vb + (size_t)row * 32;
  const float* w1 = watt + h * 32;
  const float* w2 = watt + 256 + h * 32;
  float t1 = 0.f, t2 = 0.f;
  #pragma unroll
  for (int c = 0; c < 4; ++c) {
    s16x8 v8 = *(const s16x8*)(vp + c * 8);
    #pragma unroll
    for (int e = 0; e < 8; ++e) {
      float v = __builtin_bit_cast(float, ((unsigned)(unsigned short)v8[e]) << 16);
      int d = c * 8 + e;
      t1 += v * w1[d];
      t2 += v * w2[d];
    }
  }
  vw1[row] = t1;
  vw2[row] = t2;
}

// K2: block = (bh, it), 8 waves, wave wid handles jt=wid. Two-pass streaming softmax.
// mfma(Q,K): D row = q-row (j), D col = k-row (i) => lane's i = it*16 + (lane&15) fixed.
__global__ __launch_bounds__(512, 2) void attn_kernel(
    const unsigned short* __restrict__ qb, const unsigned short* __restrict__ kb,
    const float* __restrict__ vw1, const float* __restrict__ vw2,
    float* __restrict__ attn_out, float* __restrict__ p1, float* __restrict__ p2t) {
  const int bid = blockIdx.x;                  // 512 = 64 bh * 8 it
  const int swz = (bid & 7) * 64 + (bid >> 3); // bijective XCD-chunked swizzle
  const int bh = swz >> 3, it = swz & 7;
  const int tid = threadIdx.x;
  const int wid = tid >> 6, lane = tid & 63;
  const int row16 = lane & 15, grp = lane >> 4;
  const int jt = wid;
  const int i = it * 16 + row16;

  const unsigned short* kp = kb + ((size_t)bh * 128 + i) * 1024 + grp * 8;
  const unsigned short* qp = qb + ((size_t)bh * 128 + jt * 16 + row16) * 1024 + grp * 8;
  const float* v1p = vw1 + ((size_t)bh * 128 + i) * 32;
  const float* v2p = vw2 + ((size_t)bh * 128 + i) * 32;

  const f32x4 zero = {0.f, 0.f, 0.f, 0.f};

  // pass 1: sum of exp over l (no max subtraction needed: |s| <~ 4)
  float sum[4] = {0.f, 0.f, 0.f, 0.f};
  #pragma unroll 8
  for (int l = 0; l < 32; ++l) {
    s16x8 qf = *(const s16x8*)(qp + l * 32);
    s16x8 kf = *(const s16x8*)(kp + l * 32);
    f32x4 acc = mfma16(qf, kf, zero);
    #pragma unroll
    for (int r = 0; r < 4; ++r) sum[r] += __expf(acc[r] * 0.0625f);
  }
  float inv[4];
  #pragma unroll
  for (int r = 0; r < 4; ++r) inv[r] = 1.f / sum[r];

  // pass 2: recompute, normalize, write; accumulate p1/p2 dots
  float t1[4] = {0.f, 0.f, 0.f, 0.f}, t2[4] = {0.f, 0.f, 0.f, 0.f};
  float* ob = attn_out + (((size_t)bh * 128 + i) * 128 + jt * 16 + grp * 4) * 32;
  #pragma unroll 2
  for (int lb = 0; lb < 8; ++lb) {
    f32x4 w[4];
    #pragma unroll
    for (int lo = 0; lo < 4; ++lo) {
      const int l = lb * 4 + lo;
      s16x8 qf = *(const s16x8*)(qp + l * 32);
      s16x8 kf = *(const s16x8*)(kp + l * 32);
      f32x4 acc = mfma16(qf, kf, zero);
      float v1 = v1p[l], v2 = v2p[l];
      #pragma unroll
      for (int r = 0; r < 4; ++r) {
        float e = __expf(acc[r] * 0.0625f) * inv[r];
        w[r][lo] = e;
        t1[r] += e * v1;
        t2[r] += e * v2;
      }
    }
    #pragma unroll
    for (int r = 0; r < 4; ++r)
      *(f32x4*)(ob + r * 32 + lb * 4) = w[r];
  }

  // p1[bh][i][j] (f32x4 over 4 consecutive j); p2 stored transposed: p2t[bh][j][i]
  f32x4 P1 = {t1[0], t1[1], t1[2], t1[3]};
  *(f32x4*)(p1 + ((size_t)bh * 128 + i) * 128 + jt * 16 + grp * 4) = P1;
  #pragma unroll
  for (int r = 0; r < 4; ++r)
    p2t[((size_t)bh * 128 + jt * 16 + grp * 4 + r) * 128 + i] = t2[r];
}

// K3: weight[b,i,j] = tanh(sum_h p1[b,h,i,j] + sum_h p2t[b,h,i,j] + b_att + 0.5) * (i!=j)
// (p2t[bh][i][j] holds the out^T contribution for logits[i][j])
__global__ void weight_kernel(const float* __restrict__ p1, const float* __restrict__ p2t,
                              const float* __restrict__ b_att, float* __restrict__ wout) {
  int t = blockIdx.x * 256 + threadIdx.x;   // 0..131071
  int b = t >> 14, ij = t & 16383, i = ij >> 7, j = ij & 127;
  float s = b_att[0] + 0.5f;
  #pragma unroll
  for (int h = 0; h < 8; ++h) {
    s += p1[((size_t)(b * 8 + h) * 16384) + ij];
    s += p2t[((size_t)(b * 8 + h) * 16384) + ij];
  }
  float w = tanhf(s);
  wout[t] = (i == j) ? 0.f : w;
}

extern "C" void kernel_launch(void* const* d_in, const int* in_sizes, int n_in,
                              void* d_out, int out_size, void* d_ws, size_t ws_size,
                              hipStream_t stream) {
  const float* X    = (const float*)d_in[0];   // output (L, B*A, D)
  const float* Wk   = (const float*)d_in[1];
  const float* Wq   = (const float*)d_in[2];
  const float* Wv   = (const float*)d_in[3];
  const float* Watt = (const float*)d_in[4];   // (512,1)
  const float* b_att= (const float*)d_in[5];   // (1,)

  char* ws = (char*)d_ws;
  unsigned short* wt = (unsigned short*)ws;                              // 384 KiB
  unsigned short* qb = (unsigned short*)(ws + 393216);                   // 16 MiB each
  unsigned short* kb = (unsigned short*)(ws + 393216 + 16777216);
  unsigned short* vb = (unsigned short*)(ws + 393216 + 2 * 16777216);
  float* vw1 = (float*)(ws + 393216 + 3 * 16777216);                     // 1 MiB each
  float* vw2 = (float*)(ws + 393216 + 3 * 16777216 + 1048576);
  float* p1  = (float*)(ws + 393216 + 3 * 16777216 + 2 * 1048576);       // 4 MiB each
  float* p2t = (float*)(ws + 393216 + 3 * 16777216 + 2 * 1048576 + 4194304);

  float* attn_out = (float*)d_out;                    // 33554432 floats
  float* wout     = (float*)d_out + 33554432;         // 131072 floats

  wt_kernel<<<dim3(768), dim3(256), 0, stream>>>(Wq, Wk, Wv, wt);
  proj_kernel<<<dim3(1024), dim3(256), 0, stream>>>(X, wt, qb, kb, vb);
  vw_kernel<<<dim3(1024), dim3(256), 0, stream>>>(vb, Watt, vw1, vw2);
  attn_kernel<<<dim3(512), dim3(512), 0, stream>>>(qb, kb, vw1, vw2, attn_out, p1, p2t);
  weight_kernel<<<dim3(512), dim3(256), 0, stream>>>(p1, p2t, b_att, wout);
}

// Round 3
// 172.752 us; speedup vs baseline: 1.1916x; 1.1916x over previous
//
#include <hip/hip_runtime.h>
#include <hip/hip_bf16.h>
#include <stdint.h>

// L=32, B=8, A=128, D=256, H=8, hd=32, BA=1024, M=32768
// Intermediate layout: qb/kb/vb[b][h][l][a][d]  (d=32 fastest, a=128, l=32)
//   offset = ((bh*32 + l)*128 + a)*32 + d
// vw1/vw2[bh][l][a]; p1[bh][i][j]; p2t[bh][j][i] (transposed at store)

typedef float f32x4 __attribute__((ext_vector_type(4)));
typedef short s16x8 __attribute__((ext_vector_type(8)));
typedef unsigned short u16x8 __attribute__((ext_vector_type(8)));
typedef unsigned short u16x4 __attribute__((ext_vector_type(4)));

#define EXPC 0.09016844f   // (1/16) * log2(e)

__device__ __forceinline__ unsigned short f2bf(float f) {
  __hip_bfloat16 h = __float2bfloat16(f);
  return __builtin_bit_cast(unsigned short, h);
}
__device__ __forceinline__ f32x4 mfma16(s16x8 a, s16x8 b, f32x4 c) {
  return __builtin_amdgcn_mfma_f32_16x16x32_bf16(a, b, c, 0, 0, 0);
}

// K0: Wt[s][n][k] = bf16(W_s[k][n]); s: 0=Wq 1=Wk 2=Wv
__global__ void wt_kernel(const float* __restrict__ wq, const float* __restrict__ wk,
                          const float* __restrict__ wv, unsigned short* __restrict__ wt) {
  int t = blockIdx.x * 256 + threadIdx.x;           // 0..196607
  int s = t >> 16; int w = t & 65535;
  int n = w >> 8;  int k = w & 255;
  const float* W = (s == 0) ? wq : (s == 1) ? wk : wv;
  wt[t] = f2bf(W[k * 256 + n]);
}

// K1: C_s = X(32768x256) @ W_s for s in {q,k,v}; X staged once in LDS as bf16.
// 1024 blocks x 256 thr (4 waves). Block = 32 rows of X (one (l,b,a-chunk)).
// MFMA with A=W-rows(n), B=X-rows(a) so lane holds 4 consecutive n -> LDS
// transpose [a][n] -> fully coalesced 1KB stores into [b,h,l,a,d].
__global__ __launch_bounds__(256, 3) void proj_kernel(
    const float* __restrict__ X, const unsigned short* __restrict__ wt,
    unsigned short* __restrict__ qb, unsigned short* __restrict__ kb,
    unsigned short* __restrict__ vb) {
  __shared__ unsigned short xs[32][256];   // 16 KiB input staging (granule XOR swizzle)
  __shared__ unsigned short ts[32][264];   // transpose buffer [a][n], pad 264
  const int tid = threadIdx.x;
  const int m0 = blockIdx.x * 32;

  #pragma unroll
  for (int kq = 0; kq < 4; ++kq) {
    int t = tid + kq * 256;
    int row = t >> 5, gc = t & 31;
    const float* src = X + (size_t)(m0 + row) * 256 + gc * 8;
    f32x4 f0 = *(const f32x4*)src;
    f32x4 f1 = *(const f32x4*)(src + 4);
    u16x8 o;
    #pragma unroll
    for (int e = 0; e < 4; ++e) { o[e] = f2bf(f0[e]); o[4 + e] = f2bf(f1[e]); }
    *(u16x8*)&xs[row][(gc ^ (row & 7)) * 8] = o;
  }
  __syncthreads();

  const int wid = tid >> 6, lane = tid & 63;
  const int row16 = lane & 15, grp = lane >> 4;
  const int wn = wid;  // n-chunk of 64

  f32x4 acc[3][2][4];
  #pragma unroll
  for (int s = 0; s < 3; ++s)
    #pragma unroll
    for (int mi = 0; mi < 2; ++mi)
      #pragma unroll
      for (int ni = 0; ni < 4; ++ni) acc[s][mi][ni] = (f32x4){0.f, 0.f, 0.f, 0.f};

  #pragma unroll
  for (int kk = 0; kk < 8; ++kk) {
    s16x8 xf[2];
    #pragma unroll
    for (int mi = 0; mi < 2; ++mi)
      xf[mi] = *(const s16x8*)&xs[mi * 16 + row16][((kk * 4 + grp) ^ (row16 & 7)) * 8];
    #pragma unroll
    for (int s = 0; s < 3; ++s) {
      const unsigned short* ap = wt + s * 65536 + (size_t)(wn * 64 + row16) * 256 + kk * 32 + grp * 8;
      #pragma unroll
      for (int ni = 0; ni < 4; ++ni) {
        s16x8 wf = *(const s16x8*)(ap + ni * 16 * 256);   // A = W rows (n)
        acc[s][0][ni] = mfma16(wf, xf[0], acc[s][0][ni]);
        acc[s][1][ni] = mfma16(wf, xf[1], acc[s][1][ni]);
      }
    }
  }

  const int l = m0 >> 10, b = (m0 >> 7) & 7, a0 = m0 & 127;
  #pragma unroll
  for (int s = 0; s < 3; ++s) {
    __syncthreads();
    // lane holds D[row = n-sub = grp*4+r][col = a-sub = row16]
    #pragma unroll
    for (int mi = 0; mi < 2; ++mi)
      #pragma unroll
      for (int ni = 0; ni < 4; ++ni) {
        u16x4 pk;
        #pragma unroll
        for (int r = 0; r < 4; ++r) pk[r] = f2bf(acc[s][mi][ni][r]);
        *(u16x4*)&ts[mi * 16 + row16][wn * 64 + ni * 16 + grp * 4] = pk;
      }
    __syncthreads();
    unsigned short* dst = (s == 0) ? qb : (s == 1) ? kb : vb;
    #pragma unroll
    for (int q = 0; q < 4; ++q) {
      int h = q * 2 + (tid >> 7);
      int a = (tid >> 2) & 31;
      int dg = tid & 3;
      u16x8 g8 = *(const u16x8*)&ts[a][h * 32 + dg * 8];
      size_t off = (((size_t)(b * 8 + h) * 32 + l) * 128 + a0 + a) * 32 + dg * 8;
      *(u16x8*)(dst + off) = g8;
    }
  }
}

// K1b: vw1[bh][l][a] = sum_d v*Watt[h*32+d]; vw2 with Watt[256+...]
__global__ void vw_kernel(const unsigned short* __restrict__ vb,
                          const float* __restrict__ watt,
                          float* __restrict__ vw1, float* __restrict__ vw2) {
  int row = blockIdx.x * 256 + threadIdx.x;   // (bh,l,a) flat, 0..262143
  int h = (row >> 12) & 7;
  const unsigned short* vp = vb + (size_t)row * 32;
  const float* w1 = watt + h * 32;
  const float* w2 = watt + 256 + h * 32;
  float t1 = 0.f, t2 = 0.f;
  #pragma unroll
  for (int c = 0; c < 4; ++c) {
    s16x8 v8 = *(const s16x8*)(vp + c * 8);
    #pragma unroll
    for (int e = 0; e < 8; ++e) {
      float v = __builtin_bit_cast(float, ((unsigned)(unsigned short)v8[e]) << 16);
      int d = c * 8 + e;
      t1 += v * w1[d];
      t2 += v * w2[d];
    }
  }
  vw1[row] = t1;
  vw2[row] = t2;
}

// K2: block = (bh, it, jh), 4 waves, wave w -> jt = jh*4+w. Two-pass softmax.
// Pass1 (A=Q,B=K): lane i = it*16+row16 -> contiguous vw loads, sums + p-dots.
// Pass2 (A=K,B=Q): lane i = it*16+grp*4+r -> round-1-style stores.
__global__ __launch_bounds__(256, 4) void attn_kernel(
    const unsigned short* __restrict__ qb, const unsigned short* __restrict__ kb,
    const float* __restrict__ vw1, const float* __restrict__ vw2,
    float* __restrict__ attn_out, float* __restrict__ p1, float* __restrict__ p2t) {
  __shared__ float invs[4][16][20];            // [wave][j-sub][i-sub], padded
  const int bid = blockIdx.x;                  // 1024 = 64 bh * 8 it * 2 jh
  const int swz = (bid & 7) * 128 + (bid >> 3);
  const int bh = swz >> 4, it = (swz >> 1) & 7, jh = swz & 1;
  const int tid = threadIdx.x;
  const int w = tid >> 6, lane = tid & 63;
  const int r16 = lane & 15, g = lane >> 4;
  const int jt = jh * 4 + w;

  const unsigned short* kp = kb + (size_t)bh * 131072 + (it * 16 + r16) * 32 + g * 8;
  const unsigned short* qp = qb + (size_t)bh * 131072 + (jt * 16 + r16) * 32 + g * 8;
  const float* vwp1 = vw1 + bh * 4096 + it * 16 + r16;
  const float* vwp2 = vw2 + bh * 4096 + it * 16 + r16;
  const f32x4 zero = {0.f, 0.f, 0.f, 0.f};

  // pass 1: sums + p-dots. lane pair: (i = it*16+r16, j = jt*16+g*4+r)
  float sum[4] = {0.f, 0.f, 0.f, 0.f};
  float t1[4] = {0.f, 0.f, 0.f, 0.f}, t2[4] = {0.f, 0.f, 0.f, 0.f};
  #pragma unroll 4
  for (int l = 0; l < 32; ++l) {
    s16x8 qf = *(const s16x8*)(qp + l * 4096);
    s16x8 kf = *(const s16x8*)(kp + l * 4096);
    f32x4 s4 = mfma16(qf, kf, zero);
    float v1 = vwp1[l * 128], v2 = vwp2[l * 128];
    #pragma unroll
    for (int r = 0; r < 4; ++r) {
      float e = exp2f(s4[r] * EXPC);
      sum[r] += e;
      t1[r] += e * v1;
      t2[r] += e * v2;
    }
  }
  float inv[4];
  #pragma unroll
  for (int r = 0; r < 4; ++r) inv[r] = 1.f / sum[r];
  #pragma unroll
  for (int r = 0; r < 4; ++r) {
    int i = it * 16 + r16, j = jt * 16 + g * 4 + r;
    p1[(size_t)bh * 16384 + i * 128 + j] = t1[r] * inv[r];
    p2t[(size_t)bh * 16384 + j * 128 + i] = t2[r] * inv[r];
    invs[w][g * 4 + r][r16] = inv[r];          // [j-sub][i-sub]
  }
  __syncthreads();

  // pass 2: lane pair: (i = it*16+g*4+r, j = jt*16+r16)
  f32x4 inv4 = *(const f32x4*)&invs[w][r16][g * 4];
  float* ob = attn_out + (((size_t)bh * 128 + it * 16 + g * 4) * 128 + jt * 16 + r16) * 32;
  #pragma unroll 2
  for (int lb = 0; lb < 8; ++lb) {
    f32x4 w4[4];
    #pragma unroll
    for (int lo = 0; lo < 4; ++lo) {
      const int l = lb * 4 + lo;
      s16x8 kf = *(const s16x8*)(kp + l * 4096);
      s16x8 qf = *(const s16x8*)(qp + l * 4096);
      f32x4 s4 = mfma16(kf, qf, zero);
      #pragma unroll
      for (int r = 0; r < 4; ++r) w4[r][lo] = exp2f(s4[r] * EXPC) * inv4[r];
    }
    #pragma unroll
    for (int r = 0; r < 4; ++r)
      *(f32x4*)(ob + r * 4096 + lb * 4) = w4[r];
  }
}

// K3: weight[b,i,j] = tanh(sum_h p1[b,h,i,j] + sum_h p2t[b,h,i,j] + b_att + 0.5) * (i!=j)
__global__ void weight_kernel(const float* __restrict__ p1, const float* __restrict__ p2t,
                              const float* __restrict__ b_att, float* __restrict__ wout) {
  int t = blockIdx.x * 256 + threadIdx.x;   // 0..131071
  int b = t >> 14, ij = t & 16383, i = ij >> 7, j = ij & 127;
  float s = b_att[0] + 0.5f;
  #pragma unroll
  for (int h = 0; h < 8; ++h) {
    s += p1[((size_t)(b * 8 + h) * 16384) + ij];
    s += p2t[((size_t)(b * 8 + h) * 16384) + ij];
  }
  float w = tanhf(s);
  wout[t] = (i == j) ? 0.f : w;
}

extern "C" void kernel_launch(void* const* d_in, const int* in_sizes, int n_in,
                              void* d_out, int out_size, void* d_ws, size_t ws_size,
                              hipStream_t stream) {
  const float* X    = (const float*)d_in[0];   // output (L, B*A, D)
  const float* Wk   = (const float*)d_in[1];
  const float* Wq   = (const float*)d_in[2];
  const float* Wv   = (const float*)d_in[3];
  const float* Watt = (const float*)d_in[4];   // (512,1)
  const float* b_att= (const float*)d_in[5];   // (1,)

  char* ws = (char*)d_ws;
  unsigned short* wt = (unsigned short*)ws;                              // 384 KiB
  unsigned short* qb = (unsigned short*)(ws + 393216);                   // 16 MiB each
  unsigned short* kb = (unsigned short*)(ws + 393216 + 16777216);
  unsigned short* vb = (unsigned short*)(ws + 393216 + 2 * 16777216);
  float* vw1 = (float*)(ws + 393216 + 3 * 16777216);                     // 1 MiB each
  float* vw2 = (float*)(ws + 393216 + 3 * 16777216 + 1048576);
  float* p1  = (float*)(ws + 393216 + 3 * 16777216 + 2 * 1048576);       // 4 MiB each
  float* p2t = (float*)(ws + 393216 + 3 * 16777216 + 2 * 1048576 + 4194304);

  float* attn_out = (float*)d_out;                    // 33554432 floats
  float* wout     = (float*)d_out + 33554432;         // 131072 floats

  wt_kernel<<<dim3(768), dim3(256), 0, stream>>>(Wq, Wk, Wv, wt);
  proj_kernel<<<dim3(1024), dim3(256), 0, stream>>>(X, wt, qb, kb, vb);
  vw_kernel<<<dim3(1024), dim3(256), 0, stream>>>(vb, Watt, vw1, vw2);
  attn_kernel<<<dim3(1024), dim3(256), 0, stream>>>(qb, kb, vw1, vw2, attn_out, p1, p2t);
  weight_kernel<<<dim3(512), dim3(256), 0, stream>>>(p1, p2t, b_att, wout);
}

// Round 4
// 124.043 us; speedup vs baseline: 1.6595x; 1.3927x over previous
//
#include <hip/hip_runtime.h>
#include <hip/hip_bf16.h>
#include <stdint.h>

// L=32, B=8, A=128, D=256, H=8, hd=32, BA=1024, M=32768
// Intermediate layout: qb/kb/vb[b][h][l][a][d]  (d=32 fastest, a=128, l=32)
//   offset = ((bh*32 + l)*128 + a)*32 + d
// vw1/vw2[bh][l][a]; p1[bh][i][j]; p2t[bh][j][i] (transposed at store)

typedef float f32x4 __attribute__((ext_vector_type(4)));
typedef short s16x8 __attribute__((ext_vector_type(8)));
typedef unsigned short u16x8 __attribute__((ext_vector_type(8)));
typedef unsigned short u16x4 __attribute__((ext_vector_type(4)));

#define EXPC 0.09016844f   // (1/16) * log2(e)

__device__ __forceinline__ unsigned short f2bf(float f) {
  __hip_bfloat16 h = __float2bfloat16(f);
  return __builtin_bit_cast(unsigned short, h);
}
__device__ __forceinline__ f32x4 mfma16(s16x8 a, s16x8 b, f32x4 c) {
  return __builtin_amdgcn_mfma_f32_16x16x32_bf16(a, b, c, 0, 0, 0);
}

// K0: Wt[s][n][k] = bf16(W_s[k][n]); s: 0=Wq 1=Wk 2=Wv
__global__ void wt_kernel(const float* __restrict__ wq, const float* __restrict__ wk,
                          const float* __restrict__ wv, unsigned short* __restrict__ wt) {
  int t = blockIdx.x * 256 + threadIdx.x;           // 0..196607
  int s = t >> 16; int w = t & 65535;
  int n = w >> 8;  int k = w & 255;
  const float* W = (s == 0) ? wq : (s == 1) ? wk : wv;
  wt[t] = f2bf(W[k * 256 + n]);
}

// K1: C_s = X(32768x256) @ W_s for s in {q,k,v}; X staged once in LDS as bf16.
__global__ __launch_bounds__(256, 3) void proj_kernel(
    const float* __restrict__ X, const unsigned short* __restrict__ wt,
    unsigned short* __restrict__ qb, unsigned short* __restrict__ kb,
    unsigned short* __restrict__ vb) {
  __shared__ unsigned short xs[32][256];   // 16 KiB input staging (granule XOR swizzle)
  __shared__ unsigned short ts[32][264];   // transpose buffer [a][n], pad 264
  const int tid = threadIdx.x;
  const int m0 = blockIdx.x * 32;

  #pragma unroll
  for (int kq = 0; kq < 4; ++kq) {
    int t = tid + kq * 256;
    int row = t >> 5, gc = t & 31;
    const float* src = X + (size_t)(m0 + row) * 256 + gc * 8;
    f32x4 f0 = *(const f32x4*)src;
    f32x4 f1 = *(const f32x4*)(src + 4);
    u16x8 o;
    #pragma unroll
    for (int e = 0; e < 4; ++e) { o[e] = f2bf(f0[e]); o[4 + e] = f2bf(f1[e]); }
    *(u16x8*)&xs[row][(gc ^ (row & 7)) * 8] = o;
  }
  __syncthreads();

  const int wid = tid >> 6, lane = tid & 63;
  const int row16 = lane & 15, grp = lane >> 4;
  const int wn = wid;  // n-chunk of 64

  f32x4 acc[3][2][4];
  #pragma unroll
  for (int s = 0; s < 3; ++s)
    #pragma unroll
    for (int mi = 0; mi < 2; ++mi)
      #pragma unroll
      for (int ni = 0; ni < 4; ++ni) acc[s][mi][ni] = (f32x4){0.f, 0.f, 0.f, 0.f};

  #pragma unroll
  for (int kk = 0; kk < 8; ++kk) {
    s16x8 xf[2];
    #pragma unroll
    for (int mi = 0; mi < 2; ++mi)
      xf[mi] = *(const s16x8*)&xs[mi * 16 + row16][((kk * 4 + grp) ^ (row16 & 7)) * 8];
    #pragma unroll
    for (int s = 0; s < 3; ++s) {
      const unsigned short* ap = wt + s * 65536 + (size_t)(wn * 64 + row16) * 256 + kk * 32 + grp * 8;
      #pragma unroll
      for (int ni = 0; ni < 4; ++ni) {
        s16x8 wf = *(const s16x8*)(ap + ni * 16 * 256);   // A = W rows (n)
        acc[s][0][ni] = mfma16(wf, xf[0], acc[s][0][ni]);
        acc[s][1][ni] = mfma16(wf, xf[1], acc[s][1][ni]);
      }
    }
  }

  const int l = m0 >> 10, b = (m0 >> 7) & 7, a0 = m0 & 127;
  #pragma unroll
  for (int s = 0; s < 3; ++s) {
    __syncthreads();
    #pragma unroll
    for (int mi = 0; mi < 2; ++mi)
      #pragma unroll
      for (int ni = 0; ni < 4; ++ni) {
        u16x4 pk;
        #pragma unroll
        for (int r = 0; r < 4; ++r) pk[r] = f2bf(acc[s][mi][ni][r]);
        *(u16x4*)&ts[mi * 16 + row16][wn * 64 + ni * 16 + grp * 4] = pk;
      }
    __syncthreads();
    unsigned short* dst = (s == 0) ? qb : (s == 1) ? kb : vb;
    #pragma unroll
    for (int q = 0; q < 4; ++q) {
      int h = q * 2 + (tid >> 7);
      int a = (tid >> 2) & 31;
      int dg = tid & 3;
      u16x8 g8 = *(const u16x8*)&ts[a][h * 32 + dg * 8];
      size_t off = (((size_t)(b * 8 + h) * 32 + l) * 128 + a0 + a) * 32 + dg * 8;
      *(u16x8*)(dst + off) = g8;
    }
  }
}

// K1b: vw1[bh][l][a] = sum_d v*Watt[h*32+d]; vw2 with Watt[256+...]
__global__ void vw_kernel(const unsigned short* __restrict__ vb,
                          const float* __restrict__ watt,
                          float* __restrict__ vw1, float* __restrict__ vw2) {
  int row = blockIdx.x * 256 + threadIdx.x;   // (bh,l,a) flat, 0..262143
  int h = (row >> 12) & 7;
  const unsigned short* vp = vb + (size_t)row * 32;
  const float* w1 = watt + h * 32;
  const float* w2 = watt + 256 + h * 32;
  float t1 = 0.f, t2 = 0.f;
  #pragma unroll
  for (int c = 0; c < 4; ++c) {
    s16x8 v8 = *(const s16x8*)(vp + c * 8);
    #pragma unroll
    for (int e = 0; e < 8; ++e) {
      float v = __builtin_bit_cast(float, ((unsigned)(unsigned short)v8[e]) << 16);
      int d = c * 8 + e;
      t1 += v * w1[d];
      t2 += v * w2[d];
    }
  }
  vw1[row] = t1;
  vw2[row] = t2;
}

// K2: single-pass. Block = (bh, it, jh), 4 waves, wave w -> jt = jh*4+w.
// mfma(K,Q): lane holds i = it*16+g*4+r (r=0..3), j = jt*16+r16, all 32 l in regs.
// Softmax + p-dots lane-local. Stores bounce through wave-private LDS so each
// global store is a fully-dense 1KB dwordx4.
__global__ __launch_bounds__(256, 2) void attn_kernel(
    const unsigned short* __restrict__ qb, const unsigned short* __restrict__ kb,
    const float* __restrict__ vw1, const float* __restrict__ vw2,
    float* __restrict__ attn_out, float* __restrict__ p1, float* __restrict__ p2t) {
  __shared__ float ls[4][8][64][4];            // 32 KiB; [wave][lq][pair][e]
  const int bid = blockIdx.x;                  // 1024 = 64 bh * 8 it * 2 jh
  const int swz = (bid & 7) * 128 + (bid >> 3);
  const int bh = swz >> 4, it = (swz >> 1) & 7, jh = swz & 1;
  const int tid = threadIdx.x;
  const int w = tid >> 6, lane = tid & 63;
  const int r16 = lane & 15, g = lane >> 4;
  const int jt = jh * 4 + w;

  const unsigned short* kp = kb + (size_t)bh * 131072 + (it * 16 + r16) * 32 + g * 8;
  const unsigned short* qp = qb + (size_t)bh * 131072 + (jt * 16 + r16) * 32 + g * 8;
  const float* vp1 = vw1 + bh * 4096 + it * 16 + g * 4;
  const float* vp2 = vw2 + bh * 4096 + it * 16 + g * 4;
  const f32x4 zero = {0.f, 0.f, 0.f, 0.f};

  // scores: acc[l][r] for lane's 4 (i,j) pairs
  f32x4 acc[32];
  #pragma unroll
  for (int l = 0; l < 32; ++l) {
    s16x8 kf = *(const s16x8*)(kp + l * 4096);
    s16x8 qf = *(const s16x8*)(qp + l * 4096);
    acc[l] = mfma16(kf, qf, zero);
  }

  // exp + sums + p-dots (pre-normalization)
  float sum[4] = {0.f, 0.f, 0.f, 0.f};
  float t1[4] = {0.f, 0.f, 0.f, 0.f}, t2[4] = {0.f, 0.f, 0.f, 0.f};
  #pragma unroll
  for (int l = 0; l < 32; ++l) {
    f32x4 v1 = *(const f32x4*)(vp1 + l * 128);
    f32x4 v2 = *(const f32x4*)(vp2 + l * 128);
    #pragma unroll
    for (int r = 0; r < 4; ++r) {
      float e = exp2f(acc[l][r] * EXPC);
      acc[l][r] = e;
      sum[r] += e;
      t1[r] += e * v1[r];
      t2[r] += e * v2[r];
    }
  }

  #pragma unroll
  for (int r = 0; r < 4; ++r) {
    const float inv = 1.f / sum[r];
    const int i = it * 16 + g * 4 + r, j = jt * 16 + r16;
    p1[(size_t)bh * 16384 + i * 128 + j] = t1[r] * inv;
    p2t[(size_t)bh * 16384 + j * 128 + i] = t2[r] * inv;

    // write this r's 64 (i,j) rows (128B each) to LDS
    #pragma unroll
    for (int lq = 0; lq < 8; ++lq) {
      f32x4 w4;
      #pragma unroll
      for (int e = 0; e < 4; ++e) w4[e] = acc[lq * 4 + e][r] * inv;
      *(f32x4*)&ls[w][lq][lane][0] = w4;
    }
    // read back coalesced; 8 dense 1KB stores
    #pragma unroll
    for (int t = 0; t < 8; ++t) {
      const int i_idx = t >> 1, half = t & 1;
      f32x4 d = *(const f32x4*)&ls[w][lane & 7][i_idx * 16 + half * 8 + (lane >> 3)][0];
      float* dst = attn_out + ((size_t)bh * 128 + it * 16 + i_idx * 4 + r) * 4096
                   + jt * 512 + half * 256 + lane * 4;
      *(f32x4*)dst = d;
    }
  }
}

// K3: weight[b,i,j] = tanh(sum_h p1[b,h,i,j] + sum_h p2t[b,h,i,j] + b_att + 0.5) * (i!=j)
__global__ void weight_kernel(const float* __restrict__ p1, const float* __restrict__ p2t,
                              const float* __restrict__ b_att, float* __restrict__ wout) {
  int t = blockIdx.x * 256 + threadIdx.x;   // 0..131071
  int b = t >> 14, ij = t & 16383, i = ij >> 7, j = ij & 127;
  float s = b_att[0] + 0.5f;
  #pragma unroll
  for (int h = 0; h < 8; ++h) {
    s += p1[((size_t)(b * 8 + h) * 16384) + ij];
    s += p2t[((size_t)(b * 8 + h) * 16384) + ij];
  }
  float w = tanhf(s);
  wout[t] = (i == j) ? 0.f : w;
}

extern "C" void kernel_launch(void* const* d_in, const int* in_sizes, int n_in,
                              void* d_out, int out_size, void* d_ws, size_t ws_size,
                              hipStream_t stream) {
  const float* X    = (const float*)d_in[0];   // output (L, B*A, D)
  const float* Wk   = (const float*)d_in[1];
  const float* Wq   = (const float*)d_in[2];
  const float* Wv   = (const float*)d_in[3];
  const float* Watt = (const float*)d_in[4];   // (512,1)
  const float* b_att= (const float*)d_in[5];   // (1,)

  char* ws = (char*)d_ws;
  unsigned short* wt = (unsigned short*)ws;                              // 384 KiB
  unsigned short* qb = (unsigned short*)(ws + 393216);                   // 16 MiB each
  unsigned short* kb = (unsigned short*)(ws + 393216 + 16777216);
  unsigned short* vb = (unsigned short*)(ws + 393216 + 2 * 16777216);
  float* vw1 = (float*)(ws + 393216 + 3 * 16777216);                     // 1 MiB each
  float* vw2 = (float*)(ws + 393216 + 3 * 16777216 + 1048576);
  float* p1  = (float*)(ws + 393216 + 3 * 16777216 + 2 * 1048576);       // 4 MiB each
  float* p2t = (float*)(ws + 393216 + 3 * 16777216 + 2 * 1048576 + 4194304);

  float* attn_out = (float*)d_out;                    // 33554432 floats
  float* wout     = (float*)d_out + 33554432;         // 131072 floats

  wt_kernel<<<dim3(768), dim3(256), 0, stream>>>(Wq, Wk, Wv, wt);
  proj_kernel<<<dim3(1024), dim3(256), 0, stream>>>(X, wt, qb, kb, vb);
  vw_kernel<<<dim3(1024), dim3(256), 0, stream>>>(vb, Watt, vw1, vw2);
  attn_kernel<<<dim3(1024), dim3(256), 0, stream>>>(qb, kb, vw1, vw2, attn_out, p1, p2t);
  weight_kernel<<<dim3(512), dim3(256), 0, stream>>>(p1, p2t, b_att, wout);
}

// Round 5
// 109.412 us; speedup vs baseline: 1.8814x; 1.1337x over previous
//
#include <hip/hip_runtime.h>
#include <hip/hip_bf16.h>
#include <stdint.h>

// L=32, B=8, A=128, D=256, H=8, hd=32, BA=1024, M=32768
// Intermediate layout: qb/kb/vb[b][h][l][a][d]  (d=32 fastest, a=128, l=32)
//   offset = ((bh*32 + l)*128 + a)*32 + d
// vw1/vw2[bh][l][a]; p1[bh][i][j]; p2t[bh][j][i] (transposed at store)

typedef float f32x4 __attribute__((ext_vector_type(4)));
typedef short s16x8 __attribute__((ext_vector_type(8)));
typedef unsigned short u16x8 __attribute__((ext_vector_type(8)));
typedef unsigned short u16x4 __attribute__((ext_vector_type(4)));

#define EXPC 0.09016844f   // (1/16) * log2(e)

__device__ __forceinline__ unsigned short f2bf(float f) {
  __hip_bfloat16 h = __float2bfloat16(f);
  return __builtin_bit_cast(unsigned short, h);
}
__device__ __forceinline__ f32x4 mfma16(s16x8 a, s16x8 b, f32x4 c) {
  return __builtin_amdgcn_mfma_f32_16x16x32_bf16(a, b, c, 0, 0, 0);
}

// K0: Wt[s][n][k] = bf16(W_s[k][n]); s: 0=Wq 1=Wk 2=Wv
__global__ void wt_kernel(const float* __restrict__ wq, const float* __restrict__ wk,
                          const float* __restrict__ wv, unsigned short* __restrict__ wt) {
  int t = blockIdx.x * 256 + threadIdx.x;           // 0..196607
  int s = t >> 16; int w = t & 65535;
  int n = w >> 8;  int k = w & 255;
  const float* W = (s == 0) ? wq : (s == 1) ? wk : wv;
  wt[t] = f2bf(W[k * 256 + n]);
}

// K1: C_s = X(32768x256) @ W_s for s in {q,k,v}; X staged once in LDS as bf16.
// s-OUTER accumulation: acc = 8 f32x4 only -> low VGPR pressure, deep wt prefetch.
// ts stride 280 (=140 dwords == 12 mod 32): <=2-way conflicts both phases.
__global__ __launch_bounds__(256, 3) void proj_kernel(
    const float* __restrict__ X, const unsigned short* __restrict__ wt,
    unsigned short* __restrict__ qb, unsigned short* __restrict__ kb,
    unsigned short* __restrict__ vb) {
  __shared__ unsigned short xs[32][256];   // 16 KiB input staging (granule XOR swizzle)
  __shared__ unsigned short ts[32][280];   // transpose buffer [a][n], stride 280
  const int tid = threadIdx.x;
  const int m0 = blockIdx.x * 32;

  #pragma unroll
  for (int kq = 0; kq < 4; ++kq) {
    int t = tid + kq * 256;
    int row = t >> 5, gc = t & 31;
    const float* src = X + (size_t)(m0 + row) * 256 + gc * 8;
    f32x4 f0 = *(const f32x4*)src;
    f32x4 f1 = *(const f32x4*)(src + 4);
    u16x8 o;
    #pragma unroll
    for (int e = 0; e < 4; ++e) { o[e] = f2bf(f0[e]); o[4 + e] = f2bf(f1[e]); }
    *(u16x8*)&xs[row][(gc ^ (row & 7)) * 8] = o;
  }
  __syncthreads();

  const int wid = tid >> 6, lane = tid & 63;
  const int row16 = lane & 15, grp = lane >> 4;
  const int wn = wid;  // n-chunk of 64
  const int l = m0 >> 10, b = (m0 >> 7) & 7, a0 = m0 & 127;

  for (int s = 0; s < 3; ++s) {
    f32x4 acc[2][4];
    #pragma unroll
    for (int mi = 0; mi < 2; ++mi)
      #pragma unroll
      for (int ni = 0; ni < 4; ++ni) acc[mi][ni] = (f32x4){0.f, 0.f, 0.f, 0.f};

    const unsigned short* wbase = wt + s * 65536 + (size_t)(wn * 64 + row16) * 256 + grp * 8;
    #pragma unroll
    for (int kk = 0; kk < 8; ++kk) {
      const int xc = ((kk * 4 + grp) ^ (row16 & 7)) * 8;
      s16x8 xf0 = *(const s16x8*)&xs[row16][xc];
      s16x8 xf1 = *(const s16x8*)&xs[16 + row16][xc];
      #pragma unroll
      for (int ni = 0; ni < 4; ++ni) {
        s16x8 wf = *(const s16x8*)(wbase + kk * 32 + ni * 4096);   // A = W rows (n)
        acc[0][ni] = mfma16(wf, xf0, acc[0][ni]);
        acc[1][ni] = mfma16(wf, xf1, acc[1][ni]);
      }
    }

    __syncthreads();   // previous s's ts reads complete
    #pragma unroll
    for (int mi = 0; mi < 2; ++mi)
      #pragma unroll
      for (int ni = 0; ni < 4; ++ni) {
        u16x4 pk;
        #pragma unroll
        for (int r = 0; r < 4; ++r) pk[r] = f2bf(acc[mi][ni][r]);
        *(u16x4*)&ts[mi * 16 + row16][wn * 64 + ni * 16 + grp * 4] = pk;
      }
    __syncthreads();

    unsigned short* dst = (s == 0) ? qb : (s == 1) ? kb : vb;
    #pragma unroll
    for (int q = 0; q < 4; ++q) {
      int h = q * 2 + (tid >> 7);
      int a = (tid >> 2) & 31;
      int dg = tid & 3;
      u16x8 g8 = *(const u16x8*)&ts[a][h * 32 + dg * 8];
      size_t off = (((size_t)(b * 8 + h) * 32 + l) * 128 + a0 + a) * 32 + dg * 8;
      *(u16x8*)(dst + off) = g8;
    }
  }
}

// K1b: vw1[bh][l][a] = sum_d v*Watt[h*32+d]; vw2 with Watt[256+...]
__global__ void vw_kernel(const unsigned short* __restrict__ vb,
                          const float* __restrict__ watt,
                          float* __restrict__ vw1, float* __restrict__ vw2) {
  int row = blockIdx.x * 256 + threadIdx.x;   // (bh,l,a) flat, 0..262143
  int h = (row >> 12) & 7;
  const unsigned short* vp = vb + (size_t)row * 32;
  const float* w1 = watt + h * 32;
  const float* w2 = watt + 256 + h * 32;
  float t1 = 0.f, t2 = 0.f;
  #pragma unroll
  for (int c = 0; c < 4; ++c) {
    s16x8 v8 = *(const s16x8*)(vp + c * 8);
    #pragma unroll
    for (int e = 0; e < 8; ++e) {
      float v = __builtin_bit_cast(float, ((unsigned)(unsigned short)v8[e]) << 16);
      int d = c * 8 + e;
      t1 += v * w1[d];
      t2 += v * w2[d];
    }
  }
  vw1[row] = t1;
  vw2[row] = t2;
}

// K2: single-pass. Block = (bh, it, jh), 4 waves, wave w -> jt = jh*4+w.
// mfma(K,Q): lane holds i = it*16+g*4+r (r=0..3), j = jt*16+r16, all 32 l in regs.
// Softmax + p-dots lane-local. Stores bounce through wave-private LDS so each
// global store is a fully-dense 1KB dwordx4.
__global__ __launch_bounds__(256, 2) void attn_kernel(
    const unsigned short* __restrict__ qb, const unsigned short* __restrict__ kb,
    const float* __restrict__ vw1, const float* __restrict__ vw2,
    float* __restrict__ attn_out, float* __restrict__ p1, float* __restrict__ p2t) {
  __shared__ float ls[4][8][64][4];            // 32 KiB; [wave][lq][pair][e]
  const int bid = blockIdx.x;                  // 1024 = 64 bh * 8 it * 2 jh
  const int swz = (bid & 7) * 128 + (bid >> 3);
  const int bh = swz >> 4, it = (swz >> 1) & 7, jh = swz & 1;
  const int tid = threadIdx.x;
  const int w = tid >> 6, lane = tid & 63;
  const int r16 = lane & 15, g = lane >> 4;
  const int jt = jh * 4 + w;

  const unsigned short* kp = kb + (size_t)bh * 131072 + (it * 16 + r16) * 32 + g * 8;
  const unsigned short* qp = qb + (size_t)bh * 131072 + (jt * 16 + r16) * 32 + g * 8;
  const float* vp1 = vw1 + bh * 4096 + it * 16 + g * 4;
  const float* vp2 = vw2 + bh * 4096 + it * 16 + g * 4;
  const f32x4 zero = {0.f, 0.f, 0.f, 0.f};

  // scores: acc[l][r] for lane's 4 (i,j) pairs
  f32x4 acc[32];
  #pragma unroll
  for (int l = 0; l < 32; ++l) {
    s16x8 kf = *(const s16x8*)(kp + l * 4096);
    s16x8 qf = *(const s16x8*)(qp + l * 4096);
    acc[l] = mfma16(kf, qf, zero);
  }

  // exp + sums + p-dots (pre-normalization)
  float sum[4] = {0.f, 0.f, 0.f, 0.f};
  float t1[4] = {0.f, 0.f, 0.f, 0.f}, t2[4] = {0.f, 0.f, 0.f, 0.f};
  #pragma unroll
  for (int l = 0; l < 32; ++l) {
    f32x4 v1 = *(const f32x4*)(vp1 + l * 128);
    f32x4 v2 = *(const f32x4*)(vp2 + l * 128);
    #pragma unroll
    for (int r = 0; r < 4; ++r) {
      float e = exp2f(acc[l][r] * EXPC);
      acc[l][r] = e;
      sum[r] += e;
      t1[r] += e * v1[r];
      t2[r] += e * v2[r];
    }
  }

  #pragma unroll
  for (int r = 0; r < 4; ++r) {
    const float inv = 1.f / sum[r];
    const int i = it * 16 + g * 4 + r, j = jt * 16 + r16;
    p1[(size_t)bh * 16384 + i * 128 + j] = t1[r] * inv;
    p2t[(size_t)bh * 16384 + j * 128 + i] = t2[r] * inv;

    // write this r's 64 (i,j) rows (128B each) to LDS
    #pragma unroll
    for (int lq = 0; lq < 8; ++lq) {
      f32x4 w4;
      #pragma unroll
      for (int e = 0; e < 4; ++e) w4[e] = acc[lq * 4 + e][r] * inv;
      *(f32x4*)&ls[w][lq][lane][0] = w4;
    }
    // read back coalesced; 8 dense 1KB stores
    #pragma unroll
    for (int t = 0; t < 8; ++t) {
      const int i_idx = t >> 1, half = t & 1;
      f32x4 d = *(const f32x4*)&ls[w][lane & 7][i_idx * 16 + half * 8 + (lane >> 3)][0];
      float* dst = attn_out + ((size_t)bh * 128 + it * 16 + i_idx * 4 + r) * 4096
                   + jt * 512 + half * 256 + lane * 4;
      *(f32x4*)dst = d;
    }
  }
}

// K3: weight[b,i,j] = tanh(sum_h p1[b,h,i,j] + sum_h p2t[b,h,i,j] + b_att + 0.5) * (i!=j)
__global__ void weight_kernel(const float* __restrict__ p1, const float* __restrict__ p2t,
                              const float* __restrict__ b_att, float* __restrict__ wout) {
  int t = blockIdx.x * 256 + threadIdx.x;   // 0..131071
  int b = t >> 14, ij = t & 16383, i = ij >> 7, j = ij & 127;
  float s = b_att[0] + 0.5f;
  #pragma unroll
  for (int h = 0; h < 8; ++h) {
    s += p1[((size_t)(b * 8 + h) * 16384) + ij];
    s += p2t[((size_t)(b * 8 + h) * 16384) + ij];
  }
  float w = tanhf(s);
  wout[t] = (i == j) ? 0.f : w;
}

extern "C" void kernel_launch(void* const* d_in, const int* in_sizes, int n_in,
                              void* d_out, int out_size, void* d_ws, size_t ws_size,
                              hipStream_t stream) {
  const float* X    = (const float*)d_in[0];   // output (L, B*A, D)
  const float* Wk   = (const float*)d_in[1];
  const float* Wq   = (const float*)d_in[2];
  const float* Wv   = (const float*)d_in[3];
  const float* Watt = (const float*)d_in[4];   // (512,1)
  const float* b_att= (const float*)d_in[5];   // (1,)

  char* ws = (char*)d_ws;
  unsigned short* wt = (unsigned short*)ws;                              // 384 KiB
  unsigned short* qb = (unsigned short*)(ws + 393216);                   // 16 MiB each
  unsigned short* kb = (unsigned short*)(ws + 393216 + 16777216);
  unsigned short* vb = (unsigned short*)(ws + 393216 + 2 * 16777216);
  float* vw1 = (float*)(ws + 393216 + 3 * 16777216);                     // 1 MiB each
  float* vw2 = (float*)(ws + 393216 + 3 * 16777216 + 1048576);
  float* p1  = (float*)(ws + 393216 + 3 * 16777216 + 2 * 1048576);       // 4 MiB each
  float* p2t = (float*)(ws + 393216 + 3 * 16777216 + 2 * 1048576 + 4194304);

  float* attn_out = (float*)d_out;                    // 33554432 floats
  float* wout     = (float*)d_out + 33554432;         // 131072 floats

  wt_kernel<<<dim3(768), dim3(256), 0, stream>>>(Wq, Wk, Wv, wt);
  proj_kernel<<<dim3(1024), dim3(256), 0, stream>>>(X, wt, qb, kb, vb);
  vw_kernel<<<dim3(1024), dim3(256), 0, stream>>>(vb, Watt, vw1, vw2);
  attn_kernel<<<dim3(1024), dim3(256), 0, stream>>>(qb, kb, vw1, vw2, attn_out, p1, p2t);
  weight_kernel<<<dim3(512), dim3(256), 0, stream>>>(p1, p2t, b_att, wout);
}

// Round 6
// 90.968 us; speedup vs baseline: 2.2628x; 1.2028x over previous
//
#include <hip/hip_runtime.h>
#include <hip/hip_bf16.h>
#include <stdint.h>

// L=32, B=8, A=128, D=256, H=8, hd=32, BA=1024, M=32768
// Intermediate layout: qb/kb[b][h][l][a][d]  (d=32 fastest, a=128, l=32)
//   offset = ((bh*32 + l)*128 + a)*32 + d
// vw1/vw2[bh][l][a]; p1[bh][i][j]; p2t[bh][j][i] (transposed at store)
// V GEMM eliminated: vw = X @ u, u[k][h] = sum_d Wv[k][h*32+d]*Watt[...]

typedef float f32x4 __attribute__((ext_vector_type(4)));
typedef short s16x8 __attribute__((ext_vector_type(8)));
typedef unsigned short u16x8 __attribute__((ext_vector_type(8)));
typedef unsigned short u16x4 __attribute__((ext_vector_type(4)));

#define EXPC 0.09016844f   // (1/16) * log2(e)

__device__ __forceinline__ unsigned short f2bf(float f) {
  __hip_bfloat16 h = __float2bfloat16(f);
  return __builtin_bit_cast(unsigned short, h);
}
__device__ __forceinline__ f32x4 mfma16(s16x8 a, s16x8 b, f32x4 c) {
  return __builtin_amdgcn_mfma_f32_16x16x32_bf16(a, b, c, 0, 0, 0);
}

// K0: wt[s][n][k] = bf16(W_s[k][n]) for s in {0=Wq,1=Wk};
//     ut[n][k] (n<8: u1 per h, n>=8: u2 per h): ut[n][k] = sum_d Wv[k][(n&7)*32+d]*Watt[(n>=8)*256+(n&7)*32+d]
__global__ void wt_kernel(const float* __restrict__ wq, const float* __restrict__ wk,
                          const float* __restrict__ wv, const float* __restrict__ watt,
                          unsigned short* __restrict__ wt, unsigned short* __restrict__ ut) {
  int t = blockIdx.x * 256 + threadIdx.x;           // 0..135167
  if (t < 131072) {
    int s = t >> 16; int w = t & 65535;
    int n = w >> 8;  int k = w & 255;
    const float* W = (s == 0) ? wq : wk;
    wt[t] = f2bf(W[k * 256 + n]);
  } else {
    int t2 = t - 131072;                            // 0..4095
    int n = t2 >> 8, k = t2 & 255;
    const float* wvp = wv + k * 256 + (n & 7) * 32;
    const float* wap = watt + (n >= 8 ? 256 : 0) + (n & 7) * 32;
    float s = 0.f;
    #pragma unroll
    for (int d = 0; d < 32; ++d) s += wvp[d] * wap[d];
    ut[t2] = f2bf(s);
  }
}

// K1: qb/kb = X(32768x256) @ W_s; X staged once in LDS as bf16.
// s-OUTER accumulation (8 f32x4 acc). ts stride 280: <=2-way LDS conflicts.
// Wave 3 additionally computes the 16-col u-tile -> vw1/vw2 directly.
__global__ __launch_bounds__(256, 3) void proj_kernel(
    const float* __restrict__ X, const unsigned short* __restrict__ wt,
    const unsigned short* __restrict__ ut,
    unsigned short* __restrict__ qb, unsigned short* __restrict__ kb,
    float* __restrict__ vw1, float* __restrict__ vw2) {
  __shared__ unsigned short xs[32][256];   // 16 KiB input staging (granule XOR swizzle)
  __shared__ unsigned short ts[32][280];   // transpose buffer [a][n], stride 280
  const int tid = threadIdx.x;
  const int m0 = blockIdx.x * 32;

  #pragma unroll
  for (int kq = 0; kq < 4; ++kq) {
    int t = tid + kq * 256;
    int row = t >> 5, gc = t & 31;
    const float* src = X + (size_t)(m0 + row) * 256 + gc * 8;
    f32x4 f0 = *(const f32x4*)src;
    f32x4 f1 = *(const f32x4*)(src + 4);
    u16x8 o;
    #pragma unroll
    for (int e = 0; e < 4; ++e) { o[e] = f2bf(f0[e]); o[4 + e] = f2bf(f1[e]); }
    *(u16x8*)&xs[row][(gc ^ (row & 7)) * 8] = o;
  }
  __syncthreads();

  const int wid = tid >> 6, lane = tid & 63;
  const int row16 = lane & 15, grp = lane >> 4;
  const int wn = wid;  // n-chunk of 64
  const int l = m0 >> 10, b = (m0 >> 7) & 7, a0 = m0 & 127;

  for (int s = 0; s < 2; ++s) {
    f32x4 acc[2][4];
    #pragma unroll
    for (int mi = 0; mi < 2; ++mi)
      #pragma unroll
      for (int ni = 0; ni < 4; ++ni) acc[mi][ni] = (f32x4){0.f, 0.f, 0.f, 0.f};

    const unsigned short* wbase = wt + s * 65536 + (size_t)(wn * 64 + row16) * 256 + grp * 8;
    #pragma unroll
    for (int kk = 0; kk < 8; ++kk) {
      const int xc = ((kk * 4 + grp) ^ (row16 & 7)) * 8;
      s16x8 xf0 = *(const s16x8*)&xs[row16][xc];
      s16x8 xf1 = *(const s16x8*)&xs[16 + row16][xc];
      #pragma unroll
      for (int ni = 0; ni < 4; ++ni) {
        s16x8 wf = *(const s16x8*)(wbase + kk * 32 + ni * 4096);   // A = W rows (n)
        acc[0][ni] = mfma16(wf, xf0, acc[0][ni]);
        acc[1][ni] = mfma16(wf, xf1, acc[1][ni]);
      }
    }

    __syncthreads();   // previous ts reads complete
    #pragma unroll
    for (int mi = 0; mi < 2; ++mi)
      #pragma unroll
      for (int ni = 0; ni < 4; ++ni) {
        u16x4 pk;
        #pragma unroll
        for (int r = 0; r < 4; ++r) pk[r] = f2bf(acc[mi][ni][r]);
        *(u16x4*)&ts[mi * 16 + row16][wn * 64 + ni * 16 + grp * 4] = pk;
      }
    __syncthreads();

    unsigned short* dst = (s == 0) ? qb : kb;
    #pragma unroll
    for (int q = 0; q < 4; ++q) {
      int h = q * 2 + (tid >> 7);
      int a = (tid >> 2) & 31;
      int dg = tid & 3;
      u16x8 g8 = *(const u16x8*)&ts[a][h * 32 + dg * 8];
      size_t off = (((size_t)(b * 8 + h) * 32 + l) * 128 + a0 + a) * 32 + dg * 8;
      *(u16x8*)(dst + off) = g8;
    }
  }

  // u-tile: wave 3 computes vw1/vw2 for this block's 32 agents.
  if (wid == 3) {
    const f32x4 zero = {0.f, 0.f, 0.f, 0.f};
    f32x4 au[2] = {zero, zero};
    #pragma unroll
    for (int kk = 0; kk < 8; ++kk) {
      const int xc = ((kk * 4 + grp) ^ (row16 & 7)) * 8;
      s16x8 xf0 = *(const s16x8*)&xs[row16][xc];
      s16x8 xf1 = *(const s16x8*)&xs[16 + row16][xc];
      s16x8 uf = *(const s16x8*)(ut + row16 * 256 + kk * 32 + grp * 8);  // A = u rows (n)
      au[0] = mfma16(uf, xf0, au[0]);
      au[1] = mfma16(uf, xf1, au[1]);
    }
    // lane holds D[row = n = grp*4+r][col = a-sub = row16] for mi in {0,1}
    #pragma unroll
    for (int mi = 0; mi < 2; ++mi)
      #pragma unroll
      for (int r = 0; r < 4; ++r) {
        int n = grp * 4 + r;
        float* dstv = (n < 8) ? vw1 : vw2;
        int h = n & 7;
        dstv[(size_t)(b * 8 + h) * 4096 + l * 128 + a0 + mi * 16 + row16] = au[mi][r];
      }
  }
}

// K2: single-pass. Block = (bh, it, jh), 4 waves, wave w -> jt = jh*4+w.
// mfma(K,Q): lane holds i = it*16+g*4+r (r=0..3), j = jt*16+r16, all 32 l in regs.
// Softmax + p-dots lane-local. Stores bounce through wave-private LDS so each
// global store is a fully-dense 1KB dwordx4.
__global__ __launch_bounds__(256, 2) void attn_kernel(
    const unsigned short* __restrict__ qb, const unsigned short* __restrict__ kb,
    const float* __restrict__ vw1, const float* __restrict__ vw2,
    float* __restrict__ attn_out, float* __restrict__ p1, float* __restrict__ p2t) {
  __shared__ float ls[4][8][64][4];            // 32 KiB; [wave][lq][pair][e]
  const int bid = blockIdx.x;                  // 1024 = 64 bh * 8 it * 2 jh
  const int swz = (bid & 7) * 128 + (bid >> 3);
  const int bh = swz >> 4, it = (swz >> 1) & 7, jh = swz & 1;
  const int tid = threadIdx.x;
  const int w = tid >> 6, lane = tid & 63;
  const int r16 = lane & 15, g = lane >> 4;
  const int jt = jh * 4 + w;

  const unsigned short* kp = kb + (size_t)bh * 131072 + (it * 16 + r16) * 32 + g * 8;
  const unsigned short* qp = qb + (size_t)bh * 131072 + (jt * 16 + r16) * 32 + g * 8;
  const float* vp1 = vw1 + bh * 4096 + it * 16 + g * 4;
  const float* vp2 = vw2 + bh * 4096 + it * 16 + g * 4;
  const f32x4 zero = {0.f, 0.f, 0.f, 0.f};

  // scores: acc[l][r] for lane's 4 (i,j) pairs
  f32x4 acc[32];
  #pragma unroll
  for (int l = 0; l < 32; ++l) {
    s16x8 kf = *(const s16x8*)(kp + l * 4096);
    s16x8 qf = *(const s16x8*)(qp + l * 4096);
    acc[l] = mfma16(kf, qf, zero);
  }

  // exp + sums + p-dots (pre-normalization)
  float sum[4] = {0.f, 0.f, 0.f, 0.f};
  float t1[4] = {0.f, 0.f, 0.f, 0.f}, t2[4] = {0.f, 0.f, 0.f, 0.f};
  #pragma unroll
  for (int l = 0; l < 32; ++l) {
    f32x4 v1 = *(const f32x4*)(vp1 + l * 128);
    f32x4 v2 = *(const f32x4*)(vp2 + l * 128);
    #pragma unroll
    for (int r = 0; r < 4; ++r) {
      float e = exp2f(acc[l][r] * EXPC);
      acc[l][r] = e;
      sum[r] += e;
      t1[r] += e * v1[r];
      t2[r] += e * v2[r];
    }
  }

  #pragma unroll
  for (int r = 0; r < 4; ++r) {
    const float inv = 1.f / sum[r];
    const int i = it * 16 + g * 4 + r, j = jt * 16 + r16;
    p1[(size_t)bh * 16384 + i * 128 + j] = t1[r] * inv;
    p2t[(size_t)bh * 16384 + j * 128 + i] = t2[r] * inv;

    // write this r's 64 (i,j) rows (128B each) to LDS
    #pragma unroll
    for (int lq = 0; lq < 8; ++lq) {
      f32x4 w4;
      #pragma unroll
      for (int e = 0; e < 4; ++e) w4[e] = acc[lq * 4 + e][r] * inv;
      *(f32x4*)&ls[w][lq][lane][0] = w4;
    }
    // read back coalesced; 8 dense 1KB stores
    #pragma unroll
    for (int t = 0; t < 8; ++t) {
      const int i_idx = t >> 1, half = t & 1;
      f32x4 d = *(const f32x4*)&ls[w][lane & 7][i_idx * 16 + half * 8 + (lane >> 3)][0];
      float* dst = attn_out + ((size_t)bh * 128 + it * 16 + i_idx * 4 + r) * 4096
                   + jt * 512 + half * 256 + lane * 4;
      *(f32x4*)dst = d;
    }
  }
}

// K3: weight[b,i,j] = tanh(sum_h p1[b,h,i,j] + sum_h p2t[b,h,i,j] + b_att + 0.5) * (i!=j)
__global__ void weight_kernel(const float* __restrict__ p1, const float* __restrict__ p2t,
                              const float* __restrict__ b_att, float* __restrict__ wout) {
  int t = blockIdx.x * 256 + threadIdx.x;   // 0..131071
  int b = t >> 14, ij = t & 16383, i = ij >> 7, j = ij & 127;
  float s = b_att[0] + 0.5f;
  #pragma unroll
  for (int h = 0; h < 8; ++h) {
    s += p1[((size_t)(b * 8 + h) * 16384) + ij];
    s += p2t[((size_t)(b * 8 + h) * 16384) + ij];
  }
  float w = tanhf(s);
  wout[t] = (i == j) ? 0.f : w;
}

extern "C" void kernel_launch(void* const* d_in, const int* in_sizes, int n_in,
                              void* d_out, int out_size, void* d_ws, size_t ws_size,
                              hipStream_t stream) {
  const float* X    = (const float*)d_in[0];   // output (L, B*A, D)
  const float* Wk   = (const float*)d_in[1];
  const float* Wq   = (const float*)d_in[2];
  const float* Wv   = (const float*)d_in[3];
  const float* Watt = (const float*)d_in[4];   // (512,1)
  const float* b_att= (const float*)d_in[5];   // (1,)

  char* ws = (char*)d_ws;
  unsigned short* wt = (unsigned short*)ws;                 // 256 KiB (q,k)
  unsigned short* ut = (unsigned short*)(ws + 262144);      // 8 KiB
  unsigned short* qb = (unsigned short*)(ws + 524288);      // 16 MiB each
  unsigned short* kb = (unsigned short*)(ws + 524288 + 16777216);
  float* vw1 = (float*)(ws + 524288 + 2 * 16777216);        // 1 MiB each
  float* vw2 = (float*)(ws + 524288 + 2 * 16777216 + 1048576);
  float* p1  = (float*)(ws + 524288 + 2 * 16777216 + 2 * 1048576);   // 4 MiB each
  float* p2t = (float*)(ws + 524288 + 2 * 16777216 + 2 * 1048576 + 4194304);

  float* attn_out = (float*)d_out;                    // 33554432 floats
  float* wout     = (float*)d_out + 33554432;         // 131072 floats

  wt_kernel<<<dim3(528), dim3(256), 0, stream>>>(Wq, Wk, Wv, Watt, wt, ut);
  proj_kernel<<<dim3(1024), dim3(256), 0, stream>>>(X, wt, ut, qb, kb, vw1, vw2);
  attn_kernel<<<dim3(1024), dim3(256), 0, stream>>>(qb, kb, vw1, vw2, attn_out, p1, p2t);
  weight_kernel<<<dim3(512), dim3(256), 0, stream>>>(p1, p2t, b_att, wout);
}

// Round 7
// 78.020 us; speedup vs baseline: 2.6384x; 1.1660x over previous
//
#include <hip/hip_runtime.h>
#include <hip/hip_bf16.h>
#include <stdint.h>

// L=32, B=8, A=128, D=256, H=8, hd=32, BA=1024, M=32768
// Intermediate layout: qb/kb[b][h][l][a][d]  (d=32 fastest, a=128, l=32)
//   offset = ((bh*32 + l)*128 + a)*32 + d
// vw1/vw2[bh][l][a]; p1[bh][i][j]; p2t[bh][j][i] (transposed at store)
// V GEMM eliminated: vw = X @ u, u[k][h] = sum_d Wv[k][h*32+d]*Watt[...]

typedef float f32x4 __attribute__((ext_vector_type(4)));
typedef short s16x8 __attribute__((ext_vector_type(8)));
typedef unsigned short u16x8 __attribute__((ext_vector_type(8)));
typedef unsigned short u16x4 __attribute__((ext_vector_type(4)));

#define EXPC 0.09016844f   // (1/16) * log2(e)

__device__ __forceinline__ unsigned short f2bf(float f) {
  __hip_bfloat16 h = __float2bfloat16(f);
  return __builtin_bit_cast(unsigned short, h);
}
__device__ __forceinline__ f32x4 mfma16(s16x8 a, s16x8 b, f32x4 c) {
  return __builtin_amdgcn_mfma_f32_16x16x32_bf16(a, b, c, 0, 0, 0);
}

// K0: wt[s][n][k] = bf16(W_s[k][n]) for s in {0=Wq,1=Wk};
//     ut[n][k]: n<8 -> u1 per h, n>=8 -> u2 per h
__global__ void wt_kernel(const float* __restrict__ wq, const float* __restrict__ wk,
                          const float* __restrict__ wv, const float* __restrict__ watt,
                          unsigned short* __restrict__ wt, unsigned short* __restrict__ ut) {
  int t = blockIdx.x * 256 + threadIdx.x;           // 0..135167
  if (t < 131072) {
    int s = t >> 16; int w = t & 65535;
    int n = w >> 8;  int k = w & 255;
    const float* W = (s == 0) ? wq : wk;
    wt[t] = f2bf(W[k * 256 + n]);
  } else {
    int t2 = t - 131072;                            // 0..4095
    int n = t2 >> 8, k = t2 & 255;
    const float* wvp = wv + k * 256 + (n & 7) * 32;
    const float* wap = watt + (n >= 8 ? 256 : 0) + (n & 7) * 32;
    float s = 0.f;
    #pragma unroll
    for (int d = 0; d < 32; ++d) s += wvp[d] * wap[d];
    ut[t2] = f2bf(s);
  }
}

// K1: qb/kb = X(32768x256) @ W_s; 64-row M-tiles, 512 blocks x 4 waves.
// Per wave: acc[4][4] f32x4, 16 MFMAs/kk with 4x reuse of wt and xs fragments.
// Transpose epilogue in two 32-row halves (ts stride 280, <=2-way conflicts).
// Wave 3 additionally computes the 16-col u-tile -> vw1/vw2 directly.
__global__ __launch_bounds__(256, 3) void proj_kernel(
    const float* __restrict__ X, const unsigned short* __restrict__ wt,
    const unsigned short* __restrict__ ut,
    unsigned short* __restrict__ qb, unsigned short* __restrict__ kb,
    float* __restrict__ vw1, float* __restrict__ vw2) {
  __shared__ unsigned short xs[64][256];   // 32 KiB input staging (granule XOR swizzle)
  __shared__ unsigned short ts[32][280];   // transpose buffer [a][n], stride 280
  const int tid = threadIdx.x;
  const int bid = blockIdx.x;              // 512
  const int m0 = bid * 64;
  const int l = bid >> 4, b = (bid >> 1) & 7, a0 = (bid & 1) * 64;

  #pragma unroll
  for (int kq = 0; kq < 8; ++kq) {
    int t = tid + kq * 256;
    int row = t >> 5, gc = t & 31;
    const float* src = X + (size_t)(m0 + row) * 256 + gc * 8;
    f32x4 f0 = *(const f32x4*)src;
    f32x4 f1 = *(const f32x4*)(src + 4);
    u16x8 o;
    #pragma unroll
    for (int e = 0; e < 4; ++e) { o[e] = f2bf(f0[e]); o[4 + e] = f2bf(f1[e]); }
    *(u16x8*)&xs[row][(gc ^ (row & 7)) * 8] = o;
  }
  __syncthreads();

  const int wid = tid >> 6, lane = tid & 63;
  const int row16 = lane & 15, grp = lane >> 4;
  const int wn = wid;  // n-chunk of 64

  for (int s = 0; s < 2; ++s) {
    f32x4 acc[4][4];
    #pragma unroll
    for (int mi = 0; mi < 4; ++mi)
      #pragma unroll
      for (int ni = 0; ni < 4; ++ni) acc[mi][ni] = (f32x4){0.f, 0.f, 0.f, 0.f};

    const unsigned short* wbase = wt + s * 65536 + (size_t)(wn * 64 + row16) * 256 + grp * 8;
    #pragma unroll
    for (int kk = 0; kk < 8; ++kk) {
      const int xc = ((kk * 4 + grp) ^ (row16 & 7)) * 8;
      s16x8 xf[4];
      #pragma unroll
      for (int mi = 0; mi < 4; ++mi)
        xf[mi] = *(const s16x8*)&xs[mi * 16 + row16][xc];
      s16x8 wf[4];
      #pragma unroll
      for (int ni = 0; ni < 4; ++ni)
        wf[ni] = *(const s16x8*)(wbase + kk * 32 + ni * 4096);   // A = W rows (n)
      #pragma unroll
      for (int mi = 0; mi < 4; ++mi)
        #pragma unroll
        for (int ni = 0; ni < 4; ++ni)
          acc[mi][ni] = mfma16(wf[ni], xf[mi], acc[mi][ni]);
    }

    unsigned short* dst = (s == 0) ? qb : kb;
    #pragma unroll
    for (int hh = 0; hh < 2; ++hh) {
      __syncthreads();   // previous ts reads complete
      #pragma unroll
      for (int mi2 = 0; mi2 < 2; ++mi2)
        #pragma unroll
        for (int ni = 0; ni < 4; ++ni) {
          u16x4 pk;
          #pragma unroll
          for (int r = 0; r < 4; ++r) pk[r] = f2bf(acc[hh * 2 + mi2][ni][r]);
          *(u16x4*)&ts[mi2 * 16 + row16][wn * 64 + ni * 16 + grp * 4] = pk;
        }
      __syncthreads();
      #pragma unroll
      for (int q = 0; q < 4; ++q) {
        int h = q * 2 + (tid >> 7);
        int a = (tid >> 2) & 31;
        int dg = tid & 3;
        u16x8 g8 = *(const u16x8*)&ts[a][h * 32 + dg * 8];
        size_t off = (((size_t)(b * 8 + h) * 32 + l) * 128 + a0 + hh * 32 + a) * 32 + dg * 8;
        *(u16x8*)(dst + off) = g8;
      }
    }
  }

  // u-tile: wave 3 computes vw1/vw2 for this block's 64 agents.
  if (wid == 3) {
    const f32x4 zero = {0.f, 0.f, 0.f, 0.f};
    f32x4 au[4] = {zero, zero, zero, zero};
    #pragma unroll
    for (int kk = 0; kk < 8; ++kk) {
      const int xc = ((kk * 4 + grp) ^ (row16 & 7)) * 8;
      s16x8 uf = *(const s16x8*)(ut + row16 * 256 + kk * 32 + grp * 8);  // A = u rows (n)
      #pragma unroll
      for (int mi = 0; mi < 4; ++mi) {
        s16x8 xf = *(const s16x8*)&xs[mi * 16 + row16][xc];
        au[mi] = mfma16(uf, xf, au[mi]);
      }
    }
    // lane holds D[row = n = grp*4+r][col = a-sub = row16]
    #pragma unroll
    for (int mi = 0; mi < 4; ++mi)
      #pragma unroll
      for (int r = 0; r < 4; ++r) {
        int n = grp * 4 + r;
        float* dstv = (n < 8) ? vw1 : vw2;
        int h = n & 7;
        dstv[(size_t)(b * 8 + h) * 4096 + l * 128 + a0 + mi * 16 + row16] = au[mi][r];
      }
  }
}

// K2: single-pass. Block = (bh, it, jh), 4 waves, wave w -> jt = jh*4+w.
// mfma(K,Q): lane holds i = it*16+g*4+r (r=0..3), j = jt*16+r16, all 32 l in regs.
// Softmax + p-dots lane-local. Stores bounce through wave-private LDS so each
// global store is a fully-dense 1KB dwordx4.
__global__ __launch_bounds__(256, 2) void attn_kernel(
    const unsigned short* __restrict__ qb, const unsigned short* __restrict__ kb,
    const float* __restrict__ vw1, const float* __restrict__ vw2,
    float* __restrict__ attn_out, float* __restrict__ p1, float* __restrict__ p2t) {
  __shared__ float ls[4][8][64][4];            // 32 KiB; [wave][lq][pair][e]
  const int bid = blockIdx.x;                  // 1024 = 64 bh * 8 it * 2 jh
  const int swz = (bid & 7) * 128 + (bid >> 3);
  const int bh = swz >> 4, it = (swz >> 1) & 7, jh = swz & 1;
  const int tid = threadIdx.x;
  const int w = tid >> 6, lane = tid & 63;
  const int r16 = lane & 15, g = lane >> 4;
  const int jt = jh * 4 + w;

  const unsigned short* kp = kb + (size_t)bh * 131072 + (it * 16 + r16) * 32 + g * 8;
  const unsigned short* qp = qb + (size_t)bh * 131072 + (jt * 16 + r16) * 32 + g * 8;
  const float* vp1 = vw1 + bh * 4096 + it * 16 + g * 4;
  const float* vp2 = vw2 + bh * 4096 + it * 16 + g * 4;
  const f32x4 zero = {0.f, 0.f, 0.f, 0.f};

  // scores: acc[l][r] for lane's 4 (i,j) pairs
  f32x4 acc[32];
  #pragma unroll
  for (int l = 0; l < 32; ++l) {
    s16x8 kf = *(const s16x8*)(kp + l * 4096);
    s16x8 qf = *(const s16x8*)(qp + l * 4096);
    acc[l] = mfma16(kf, qf, zero);
  }

  // exp + sums + p-dots (pre-normalization)
  float sum[4] = {0.f, 0.f, 0.f, 0.f};
  float t1[4] = {0.f, 0.f, 0.f, 0.f}, t2[4] = {0.f, 0.f, 0.f, 0.f};
  #pragma unroll
  for (int l = 0; l < 32; ++l) {
    f32x4 v1 = *(const f32x4*)(vp1 + l * 128);
    f32x4 v2 = *(const f32x4*)(vp2 + l * 128);
    #pragma unroll
    for (int r = 0; r < 4; ++r) {
      float e = exp2f(acc[l][r] * EXPC);
      acc[l][r] = e;
      sum[r] += e;
      t1[r] += e * v1[r];
      t2[r] += e * v2[r];
    }
  }

  #pragma unroll
  for (int r = 0; r < 4; ++r) {
    const float inv = 1.f / sum[r];
    const int i = it * 16 + g * 4 + r, j = jt * 16 + r16;
    p1[(size_t)bh * 16384 + i * 128 + j] = t1[r] * inv;
    p2t[(size_t)bh * 16384 + j * 128 + i] = t2[r] * inv;

    // write this r's 64 (i,j) rows (128B each) to LDS
    #pragma unroll
    for (int lq = 0; lq < 8; ++lq) {
      f32x4 w4;
      #pragma unroll
      for (int e = 0; e < 4; ++e) w4[e] = acc[lq * 4 + e][r] * inv;
      *(f32x4*)&ls[w][lq][lane][0] = w4;
    }
    // read back coalesced; 8 dense 1KB stores
    #pragma unroll
    for (int t = 0; t < 8; ++t) {
      const int i_idx = t >> 1, half = t & 1;
      f32x4 d = *(const f32x4*)&ls[w][lane & 7][i_idx * 16 + half * 8 + (lane >> 3)][0];
      float* dst = attn_out + ((size_t)bh * 128 + it * 16 + i_idx * 4 + r) * 4096
                   + jt * 512 + half * 256 + lane * 4;
      *(f32x4*)dst = d;
    }
  }
}

// K3: weight[b,i,j] = tanh(sum_h p1[b,h,i,j] + sum_h p2t[b,h,i,j] + b_att + 0.5) * (i!=j)
__global__ void weight_kernel(const float* __restrict__ p1, const float* __restrict__ p2t,
                              const float* __restrict__ b_att, float* __restrict__ wout) {
  int t = blockIdx.x * 256 + threadIdx.x;   // 0..131071
  int b = t >> 14, ij = t & 16383, i = ij >> 7, j = ij & 127;
  float s = b_att[0] + 0.5f;
  #pragma unroll
  for (int h = 0; h < 8; ++h) {
    s += p1[((size_t)(b * 8 + h) * 16384) + ij];
    s += p2t[((size_t)(b * 8 + h) * 16384) + ij];
  }
  float w = tanhf(s);
  wout[t] = (i == j) ? 0.f : w;
}

extern "C" void kernel_launch(void* const* d_in, const int* in_sizes, int n_in,
                              void* d_out, int out_size, void* d_ws, size_t ws_size,
                              hipStream_t stream) {
  const float* X    = (const float*)d_in[0];   // output (L, B*A, D)
  const float* Wk   = (const float*)d_in[1];
  const float* Wq   = (const float*)d_in[2];
  const float* Wv   = (const float*)d_in[3];
  const float* Watt = (const float*)d_in[4];   // (512,1)
  const float* b_att= (const float*)d_in[5];   // (1,)

  char* ws = (char*)d_ws;
  unsigned short* wt = (unsigned short*)ws;                 // 256 KiB (q,k)
  unsigned short* ut = (unsigned short*)(ws + 262144);      // 8 KiB
  unsigned short* qb = (unsigned short*)(ws + 524288);      // 16 MiB each
  unsigned short* kb = (unsigned short*)(ws + 524288 + 16777216);
  float* vw1 = (float*)(ws + 524288 + 2 * 16777216);        // 1 MiB each
  float* vw2 = (float*)(ws + 524288 + 2 * 16777216 + 1048576);
  float* p1  = (float*)(ws + 524288 + 2 * 16777216 + 2 * 1048576);   // 4 MiB each
  float* p2t = (float*)(ws + 524288 + 2 * 16777216 + 2 * 1048576 + 4194304);

  float* attn_out = (float*)d_out;                    // 33554432 floats
  float* wout     = (float*)d_out + 33554432;         // 131072 floats

  wt_kernel<<<dim3(528), dim3(256), 0, stream>>>(Wq, Wk, Wv, Watt, wt, ut);
  proj_kernel<<<dim3(512), dim3(256), 0, stream>>>(X, wt, ut, qb, kb, vw1, vw2);
  attn_kernel<<<dim3(1024), dim3(256), 0, stream>>>(qb, kb, vw1, vw2, attn_out, p1, p2t);
  weight_kernel<<<dim3(512), dim3(256), 0, stream>>>(p1, p2t, b_att, wout);
}